// Round 2
// baseline (463.228 us; speedup 1.0000x reference)
//
#include <hip/hip_runtime.h>
#include <stdint.h>

static constexpr int KD = 4096;   // inner dim
static constexpr int ND = 4096;   // output features

using i32x4  = __attribute__((ext_vector_type(4)))  int;
using i32x16 = __attribute__((ext_vector_type(16))) int;

__device__ __forceinline__ void async_copy16(const void* g, void* l) {
    __builtin_amdgcn_global_load_lds(
        (const __attribute__((address_space(1))) void*)g,
        (__attribute__((address_space(3))) void*)l,
        16, 0, 0);
}

// ---------------------------------------------------------------- absmax ----
__global__ __launch_bounds__(256) void absmax_kernel(
        const float* __restrict__ x, unsigned* __restrict__ out_bits, int n4) {
    int tid = blockIdx.x * blockDim.x + threadIdx.x;
    int stride = gridDim.x * blockDim.x;
    const float4* x4 = (const float4*)x;
    float m0 = 0.f, m1 = 0.f, m2 = 0.f, m3 = 0.f;
    // n4 is a multiple of 4*stride for our shapes; 4 independent accumulators
    for (int i = tid; i < n4; i += 4 * stride) {
        float4 a = x4[i];
        float4 b = x4[i + stride];
        float4 c = x4[i + 2 * stride];
        float4 d = x4[i + 3 * stride];
        m0 = fmaxf(m0, fmaxf(fmaxf(fabsf(a.x), fabsf(a.y)),
                             fmaxf(fabsf(a.z), fabsf(a.w))));
        m1 = fmaxf(m1, fmaxf(fmaxf(fabsf(b.x), fabsf(b.y)),
                             fmaxf(fabsf(b.z), fabsf(b.w))));
        m2 = fmaxf(m2, fmaxf(fmaxf(fabsf(c.x), fabsf(c.y)),
                             fmaxf(fabsf(c.z), fabsf(c.w))));
        m3 = fmaxf(m3, fmaxf(fmaxf(fabsf(d.x), fabsf(d.y)),
                             fmaxf(fabsf(d.z), fabsf(d.w))));
    }
    float m = fmaxf(fmaxf(m0, m1), fmaxf(m2, m3));
    #pragma unroll
    for (int off = 32; off > 0; off >>= 1)
        m = fmaxf(m, __shfl_down(m, off, 64));
    __shared__ float wmax[4];
    int lane = threadIdx.x & 63, w = threadIdx.x >> 6;
    if (lane == 0) wmax[w] = m;
    __syncthreads();
    if (threadIdx.x == 0) {
        float b = fmaxf(fmaxf(wmax[0], wmax[1]), fmaxf(wmax[2], wmax[3]));
        // all values >= 0: uint bit-pattern order == float order
        atomicMax(out_bits, __float_as_uint(b));
    }
}

// ------------------------------------------------------------- quantize x ---
// q = (int8)trunc(clip(x / (max/127), -127, 127))  -- IEEE div, trunc-to-zero
// one float4 per thread (16B/lane unit stride read, 4B/lane packed write)
__global__ __launch_bounds__(256) void quant_x_kernel(
        const float* __restrict__ x, const unsigned* __restrict__ mx_bits,
        int8_t* __restrict__ xq) {
    int tid = blockIdx.x * blockDim.x + threadIdx.x;
    float s = __uint_as_float(*mx_bits) / 127.0f;
    float4 v = ((const float4*)x)[tid];
    float t0 = fminf(127.f, fmaxf(-127.f, v.x / s));
    float t1 = fminf(127.f, fmaxf(-127.f, v.y / s));
    float t2 = fminf(127.f, fmaxf(-127.f, v.z / s));
    float t3 = fminf(127.f, fmaxf(-127.f, v.w / s));
    int q0 = (int)t0, q1 = (int)t1, q2 = (int)t2, q3 = (int)t3;
    ((int*)xq)[tid] = (q0 & 255) | ((q1 & 255) << 8) | ((q2 & 255) << 16) | (q3 << 24);
}

// ------------------------------------------------------ pack weight i32->i8 -
__global__ __launch_bounds__(256) void pack_w_kernel(
        const int* __restrict__ w, int8_t* __restrict__ wq) {
    int tid = blockIdx.x * blockDim.x + threadIdx.x;
    int4 v = ((const int4*)w)[tid];
    ((int*)wq)[tid] = (v.x & 255) | ((v.y & 255) << 8) | ((v.z & 255) << 16) | (v.w << 24);
}

// ------------------------------------------------------------------ GEMM ----
// C[m][n] = sum_k Aq[m][k] * Wq[n][k]; epilogue: *stot + bias[n]
// 128x128 tile, BK=64 bytes, 4 waves (2x2), each wave 2x2 MFMA 32x32x32 tiles.
__global__ __launch_bounds__(256) void gemm_i8_kernel(
        const int8_t* __restrict__ Aq,        // M x K
        const int8_t* __restrict__ Wq,        // N x K
        const unsigned* __restrict__ mx_bits,
        const float* __restrict__ wscale_p,
        const float* __restrict__ bias,
        float* __restrict__ out) {
    __shared__ __align__(16) int8_t lds_a[128 * 64];
    __shared__ __align__(16) int8_t lds_b[128 * 64];

    const int bx = blockIdx.x;                // n tile
    const int by = blockIdx.y;                // m tile
    const int tid  = threadIdx.x;
    const int lane = tid & 63;
    const int w    = tid >> 6;
    const int wm = (w >> 1) * 64;
    const int wn = (w & 1) * 64;
    const int r32 = lane & 31;                // row within 32-tile
    const int kh  = lane >> 5;                // k-half 0/1 (16B each within K=32)

    // staging: 512 chunks of 16B per tile; thread handles slots tid, tid+256.
    // LDS[row][cl] holds global chunk (cl ^ ((row>>1)&3)) of that row.
    const int r1 = tid >> 2;
    const int c1 = (tid & 3) ^ ((tid >> 3) & 3);
    const int r2 = r1 + 64;
    const size_t Abase = (size_t)by * 128 * KD;
    const size_t Bbase = (size_t)bx * 128 * KD;
    int8_t* ldsA1 = lds_a + (tid & 192) * 16;          // wave-uniform bases
    int8_t* ldsA2 = lds_a + 4096 + (tid & 192) * 16;
    int8_t* ldsB1 = lds_b + (tid & 192) * 16;
    int8_t* ldsB2 = lds_b + 4096 + (tid & 192) * 16;

    i32x16 acc[2][2] = {};

    for (int kt = 0; kt < KD / 64; ++kt) {
        const int k0 = kt * 64;
        async_copy16(Aq + Abase + (size_t)r1 * KD + k0 + c1 * 16, ldsA1);
        async_copy16(Aq + Abase + (size_t)r2 * KD + k0 + c1 * 16, ldsA2);
        async_copy16(Wq + Bbase + (size_t)r1 * KD + k0 + c1 * 16, ldsB1);
        async_copy16(Wq + Bbase + (size_t)r2 * KD + k0 + c1 * 16, ldsB2);
        __syncthreads();

        i32x4 af[2][2], bf[2][2];              // [kk][tile]
        #pragma unroll
        for (int i = 0; i < 2; ++i) {
            int row = wm + i * 32 + r32;
            int sw = (row >> 1) & 3;
            #pragma unroll
            for (int kk = 0; kk < 2; ++kk)
                af[kk][i] = *(const i32x4*)(lds_a + row * 64 +
                                            (((kk * 2 + kh) ^ sw) << 4));
        }
        #pragma unroll
        for (int j = 0; j < 2; ++j) {
            int row = wn + j * 32 + r32;
            int sw = (row >> 1) & 3;
            #pragma unroll
            for (int kk = 0; kk < 2; ++kk)
                bf[kk][j] = *(const i32x4*)(lds_b + row * 64 +
                                            (((kk * 2 + kh) ^ sw) << 4));
        }
        #pragma unroll
        for (int kk = 0; kk < 2; ++kk)
            #pragma unroll
            for (int i = 0; i < 2; ++i)
                #pragma unroll
                for (int j = 0; j < 2; ++j)
                    acc[i][j] = __builtin_amdgcn_mfma_i32_32x32x32_i8(
                        af[kk][i], bf[kk][j], acc[i][j], 0, 0, 0);
        __syncthreads();
    }

    const float stot = (__uint_as_float(*mx_bits) / 127.0f) * (*wscale_p);
    const int rquad = (lane >> 5) * 4;         // row offset from lane half
    float bj[2];
    #pragma unroll
    for (int j = 0; j < 2; ++j)
        bj[j] = bias[bx * 128 + wn + j * 32 + r32];

    #pragma unroll
    for (int i = 0; i < 2; ++i) {
        #pragma unroll
        for (int reg = 0; reg < 16; ++reg) {
            int row_in = (reg & 3) + 8 * (reg >> 2) + rquad;
            float* orow = out + (size_t)(by * 128 + wm + i * 32 + row_in) * ND
                              + bx * 128;
            #pragma unroll
            for (int j = 0; j < 2; ++j)
                orow[wn + j * 32 + r32] = (float)acc[i][j][reg] * stot + bj[j];
        }
    }
}

// ---------------------------------------------------------------- launch ----
extern "C" void kernel_launch(void* const* d_in, const int* in_sizes, int n_in,
                              void* d_out, int out_size, void* d_ws, size_t ws_size,
                              hipStream_t stream) {
    const float* x      = (const float*)d_in[0];
    const int*   wgt    = (const int*)d_in[1];     // int8 values widened to i32
    const float* wscale = (const float*)d_in[2];
    const float* bias   = (const float*)d_in[3];
    float* out = (float*)d_out;

    const int M = in_sizes[0] / KD;                // 8192

    uint8_t* ws = (uint8_t*)d_ws;
    unsigned* mx_bits = (unsigned*)ws;
    int8_t* xq = (int8_t*)(ws + 256);
    int8_t* wq = (int8_t*)(ws + 256 + (size_t)M * KD);

    hipMemsetAsync(mx_bits, 0, 4, stream);
    absmax_kernel<<<2048, 256, 0, stream>>>(x, mx_bits, (M * KD) / 4);
    quant_x_kernel<<<(M * KD / 4) / 256, 256, 0, stream>>>(x, mx_bits, xq);
    pack_w_kernel<<<(ND * KD / 4) / 256, 256, 0, stream>>>(wgt, wq);
    gemm_i8_kernel<<<dim3(ND / 128, M / 128), 256, 0, stream>>>(
        xq, wq, mx_bits, wscale, bias, out);
}

// Round 3
// 426.690 us; speedup vs baseline: 1.0856x; 1.0856x over previous
//
#include <hip/hip_runtime.h>
#include <stdint.h>

static constexpr int KD = 4096;   // inner dim
static constexpr int ND = 4096;   // output features
static constexpr int BKB = 128;   // K-bytes staged per barrier

using i32x4 = __attribute__((ext_vector_type(4))) int;

__device__ __forceinline__ void async_copy16(const void* g, void* l) {
    __builtin_amdgcn_global_load_lds(
        (const __attribute__((address_space(1))) void*)g,
        (__attribute__((address_space(3))) void*)l,
        16, 0, 0);
}

// ---------------------------------------------- fused absmax + weight pack --
// blocks [0, AB_BLOCKS): grid-stride absmax over x (float4, 4 accumulators)
// blocks [AB_BLOCKS, AB_BLOCKS+PK_BLOCKS): pack weight i32 -> i8 (16/thread)
static constexpr int AB_BLOCKS = 2048;

__global__ __launch_bounds__(256) void prologue_kernel(
        const float* __restrict__ x, unsigned* __restrict__ out_bits, int n4,
        const int* __restrict__ w, int8_t* __restrict__ wq) {
    if (blockIdx.x < AB_BLOCKS) {
        int tid = blockIdx.x * blockDim.x + threadIdx.x;
        int stride = AB_BLOCKS * 256;
        const float4* x4 = (const float4*)x;
        float m0 = 0.f, m1 = 0.f, m2 = 0.f, m3 = 0.f;
        for (int i = tid; i < n4; i += 4 * stride) {
            float4 a = x4[i];
            float4 b = x4[i + stride];
            float4 c = x4[i + 2 * stride];
            float4 d = x4[i + 3 * stride];
            m0 = fmaxf(m0, fmaxf(fmaxf(fabsf(a.x), fabsf(a.y)),
                                 fmaxf(fabsf(a.z), fabsf(a.w))));
            m1 = fmaxf(m1, fmaxf(fmaxf(fabsf(b.x), fabsf(b.y)),
                                 fmaxf(fabsf(b.z), fabsf(b.w))));
            m2 = fmaxf(m2, fmaxf(fmaxf(fabsf(c.x), fabsf(c.y)),
                                 fmaxf(fabsf(c.z), fabsf(c.w))));
            m3 = fmaxf(m3, fmaxf(fmaxf(fabsf(d.x), fabsf(d.y)),
                                 fmaxf(fabsf(d.z), fabsf(d.w))));
        }
        float m = fmaxf(fmaxf(m0, m1), fmaxf(m2, m3));
        #pragma unroll
        for (int off = 32; off > 0; off >>= 1)
            m = fmaxf(m, __shfl_down(m, off, 64));
        __shared__ float wmax[4];
        int lane = threadIdx.x & 63, wv = threadIdx.x >> 6;
        if (lane == 0) wmax[wv] = m;
        __syncthreads();
        if (threadIdx.x == 0) {
            float b = fmaxf(fmaxf(wmax[0], wmax[1]), fmaxf(wmax[2], wmax[3]));
            atomicMax(out_bits, __float_as_uint(b));   // all >=0: bit order ok
        }
    } else {
        // pack: 16 int8 per thread (64B contiguous read, 16B write)
        int t = (blockIdx.x - AB_BLOCKS) * 256 + threadIdx.x;
        const int4* w4 = (const int4*)(w) + (size_t)t * 4;
        int4 packed;
        int* pp = (int*)&packed;
        #pragma unroll
        for (int g = 0; g < 4; ++g) {
            int4 v = w4[g];
            pp[g] = (v.x & 255) | ((v.y & 255) << 8) |
                    ((v.z & 255) << 16) | (v.w << 24);
        }
        ((int4*)wq)[t] = packed;
    }
}

// ------------------------------------------------------------- quantize x ---
// q = (int8)trunc(clip(x / (max/127), -127, 127))  -- IEEE div, trunc-to-zero
__global__ __launch_bounds__(256) void quant_x_kernel(
        const float* __restrict__ x, const unsigned* __restrict__ mx_bits,
        int8_t* __restrict__ xq) {
    int tid = blockIdx.x * blockDim.x + threadIdx.x;
    float s = __uint_as_float(*mx_bits) / 127.0f;
    float4 v = ((const float4*)x)[tid];
    float t0 = fminf(127.f, fmaxf(-127.f, v.x / s));
    float t1 = fminf(127.f, fmaxf(-127.f, v.y / s));
    float t2 = fminf(127.f, fmaxf(-127.f, v.z / s));
    float t3 = fminf(127.f, fmaxf(-127.f, v.w / s));
    int q0 = (int)t0, q1 = (int)t1, q2 = (int)t2, q3 = (int)t3;
    ((int*)xq)[tid] = (q0 & 255) | ((q1 & 255) << 8) |
                      ((q2 & 255) << 16) | (q3 << 24);
}

// ------------------------------------------------------------------ GEMM ----
// C[m][n] = sum_k Aq[m][k] * Wq[n][k]; epilogue: *stot + bias[n]
// 128x128 tile, BK=128 bytes, 4 waves (2x2), 4x4 MFMA 16x16x64 tiles per wave,
// 2 K-steps per barrier (32 MFMA / barrier).
// LDS row = 128B. Swizzle: LDS[row][c] holds global 16B chunk (c ^ (row&7)).
// Fragment reads: 8-lane groups (fixed kc, rows r..r+7) cover all 32 banks
// exactly once -> conflict-free ds_read_b128.
__global__ __launch_bounds__(256) void gemm_i8_kernel(
        const int8_t* __restrict__ Aq,        // M x K
        const int8_t* __restrict__ Wq,        // N x K
        const unsigned* __restrict__ mx_bits,
        const float* __restrict__ wscale_p,
        const float* __restrict__ bias,
        float* __restrict__ out) {
    __shared__ __align__(16) int8_t lds_a[128 * BKB];
    __shared__ __align__(16) int8_t lds_b[128 * BKB];

    const int bx = blockIdx.x;                // n tile
    const int by = blockIdx.y;                // m tile
    const int tid  = threadIdx.x;
    const int lane = tid & 63;
    const int w    = tid >> 6;
    const int wm = (w >> 1) * 64;
    const int wn = (w & 1) * 64;
    const int fr = lane & 15;                 // row within 16-tile
    const int kc = lane >> 4;                 // 16B chunk within 64B k-step

    // staging: 1024 chunks/tile; thread handles slots {c*256+tid : c=0..3}.
    const int rr  = tid >> 3;                 // row within 32-row copy group
    const int gch = (tid & 7) ^ ((tid >> 3) & 7);   // swizzled global chunk
    const size_t Abase = (size_t)by * 128 * KD + (size_t)rr * KD + gch * 16;
    const size_t Bbase = (size_t)bx * 128 * KD + (size_t)rr * KD + gch * 16;
    const int ldsoff = (tid & 192) * 16;      // wave-uniform lane-block base

    i32x4 acc[4][4] = {};

    for (int kt = 0; kt < KD / BKB; ++kt) {
        const int kb = kt * BKB;
        #pragma unroll
        for (int c = 0; c < 4; ++c) {
            async_copy16(Aq + Abase + (size_t)(c * 32) * KD + kb,
                         lds_a + c * 4096 + ldsoff);
            async_copy16(Wq + Bbase + (size_t)(c * 32) * KD + kb,
                         lds_b + c * 4096 + ldsoff);
        }
        __syncthreads();

        #pragma unroll
        for (int s = 0; s < 2; ++s) {
            i32x4 af[4], bf[4];
            #pragma unroll
            for (int i = 0; i < 4; ++i) {
                int row = wm + i * 16 + fr;
                int lc = (s * 4 + kc) ^ (row & 7);
                af[i] = *(const i32x4*)(lds_a + row * BKB + lc * 16);
            }
            #pragma unroll
            for (int j = 0; j < 4; ++j) {
                int row = wn + j * 16 + fr;
                int lc = (s * 4 + kc) ^ (row & 7);
                bf[j] = *(const i32x4*)(lds_b + row * BKB + lc * 16);
            }
            #pragma unroll
            for (int i = 0; i < 4; ++i)
                #pragma unroll
                for (int j = 0; j < 4; ++j)
                    acc[i][j] = __builtin_amdgcn_mfma_i32_16x16x64_i8(
                        af[i], bf[j], acc[i][j], 0, 0, 0);
        }
        __syncthreads();
    }

    const float stot = (__uint_as_float(*mx_bits) / 127.0f) * (*wscale_p);
    float bj[4];
    #pragma unroll
    for (int j = 0; j < 4; ++j)
        bj[j] = bias[bx * 128 + wn + j * 16 + fr];

    #pragma unroll
    for (int i = 0; i < 4; ++i) {
        int mrow = by * 128 + wm + i * 16 + kc * 4;    // + reg index r
        #pragma unroll
        for (int r = 0; r < 4; ++r) {
            float* orow = out + (size_t)(mrow + r) * ND + bx * 128;
            #pragma unroll
            for (int j = 0; j < 4; ++j)
                orow[wn + j * 16 + fr] = (float)acc[i][j][r] * stot + bj[j];
        }
    }
}

// ---------------------------------------------------------------- launch ----
extern "C" void kernel_launch(void* const* d_in, const int* in_sizes, int n_in,
                              void* d_out, int out_size, void* d_ws, size_t ws_size,
                              hipStream_t stream) {
    const float* x      = (const float*)d_in[0];
    const int*   wgt    = (const int*)d_in[1];     // int8 values widened to i32
    const float* wscale = (const float*)d_in[2];
    const float* bias   = (const float*)d_in[3];
    float* out = (float*)d_out;

    const int M = in_sizes[0] / KD;                // 8192

    uint8_t* ws = (uint8_t*)d_ws;
    unsigned* mx_bits = (unsigned*)ws;
    int8_t* xq = (int8_t*)(ws + 256);
    int8_t* wq = (int8_t*)(ws + 256 + (size_t)M * KD);

    const int pk_blocks = (ND * KD / 16) / 256;    // 4096
    hipMemsetAsync(mx_bits, 0, 4, stream);
    prologue_kernel<<<AB_BLOCKS + pk_blocks, 256, 0, stream>>>(
        x, mx_bits, (M * KD) / 4, wgt, wq);
    quant_x_kernel<<<(M * KD / 4) / 256, 256, 0, stream>>>(x, mx_bits, xq);
    gemm_i8_kernel<<<dim3(ND / 128, M / 128), 256, 0, stream>>>(
        xq, wq, mx_bits, wscale, bias, out);
}